// Round 1
// baseline (106.640 us; speedup 1.0000x reference)
//
#include <hip/hip_runtime.h>

#define H 128

typedef float f2 __attribute__((ext_vector_type(2)));

// ---------------------------------------------------------------------------
// Kernel 1: fused 3-layer MLP + Ws1 projection for agents AND regions.
//   agent blocks: pa[a][:] = relu(relu(xA@Wa1+ba1)@Wa2+ba2) @ Ws1[:128] + bs1
//   region blocks: pr[r][:] = relu(relu(xR@Wr1+br1)@Wr2+br2) @ Ws1[128:]
// (bs1 folded into pa so the pair kernel only does pa+pr.)
// Block = 128 threads (thread j owns output column j), 8 rows per block.
// ---------------------------------------------------------------------------
__global__ __launch_bounds__(128) void emb_kernel(
    const float* __restrict__ xA, const float* __restrict__ xR,
    const float* __restrict__ Wa1, const float* __restrict__ ba1,
    const float* __restrict__ Wa2, const float* __restrict__ ba2,
    const float* __restrict__ Wr1, const float* __restrict__ br1,
    const float* __restrict__ Wr2, const float* __restrict__ br2,
    const float* __restrict__ Ws1, const float* __restrict__ bs1,
    float* __restrict__ pa, float* __restrict__ pr,
    int na, int nr)
{
    const int ROWS = 8;
    const int b = blockIdx.x;
    const int nblkA = na / ROWS;
    const bool isA = (b < nblkA);                 // wave-uniform branch
    const int row0 = (isA ? b : b - nblkA) * ROWS;
    const float* __restrict__ x  = isA ? xA : xR;
    const float* __restrict__ W1 = isA ? Wa1 : Wr1;
    const float* __restrict__ b1 = isA ? ba1 : br1;
    const float* __restrict__ W2 = isA ? Wa2 : Wr2;
    const float* __restrict__ b2 = isA ? ba2 : br2;
    const float* __restrict__ W3 = isA ? Ws1 : Ws1 + H * H; // Ws1_a / Ws1_r
    float* __restrict__ outp     = isA ? pa : pr;
    const int in_dim = isA ? 24 : 20;

    __shared__ float sX[ROWS][24];
    __shared__ float sH[ROWS][H];

    const int j = threadIdx.x;

    // stage x rows (zero-pad columns >= in_dim so a fixed-24 unroll is safe)
    #pragma unroll
    for (int t = 0; t < 2; ++t) {
        int idx = t * 128 + j;
        if (idx < ROWS * 24) {
            int r = idx / 24, k = idx - r * 24;
            sX[r][k] = (k < in_dim) ? x[(row0 + r) * in_dim + k] : 0.f;
        }
    }
    __syncthreads();

    // ---- layer 1: h1 = relu(x @ W1 + b1) ----
    float w1[24];
    #pragma unroll
    for (int k = 0; k < 24; ++k)
        w1[k] = (k < in_dim) ? W1[k * H + j] : 0.f;   // predicated, no OOB
    {
        const float bj = b1[j];
        #pragma unroll
        for (int r = 0; r < ROWS; ++r) {
            float s = bj;
            #pragma unroll
            for (int k = 0; k < 24; ++k) s += sX[r][k] * w1[k];
            sH[r][j] = fmaxf(s, 0.f);
        }
    }
    __syncthreads();

    float acc[ROWS];
    // ---- layer 2: h2 = relu(h1 @ W2 + b2) ----
    {
        const float bj = b2[j];
        #pragma unroll
        for (int r = 0; r < ROWS; ++r) acc[r] = bj;
    }
    #pragma unroll
    for (int kc = 0; kc < H; kc += 32) {
        float w2[32];
        #pragma unroll
        for (int kk = 0; kk < 32; ++kk) w2[kk] = W2[(kc + kk) * H + j];
        #pragma unroll
        for (int r = 0; r < ROWS; ++r) {
            float s = acc[r];
            #pragma unroll
            for (int kk = 0; kk < 32; ++kk) s += sH[r][kc + kk] * w2[kk];
            acc[r] = s;
        }
    }
    __syncthreads();
    #pragma unroll
    for (int r = 0; r < ROWS; ++r) sH[r][j] = fmaxf(acc[r], 0.f);
    __syncthreads();

    // ---- layer 3 (projection): p = h2 @ W3 (+ bs1 on agent side) ----
    {
        const float init = isA ? bs1[j] : 0.f;
        #pragma unroll
        for (int r = 0; r < ROWS; ++r) acc[r] = init;
    }
    #pragma unroll
    for (int kc = 0; kc < H; kc += 32) {
        float w3[32];
        #pragma unroll
        for (int kk = 0; kk < 32; ++kk) w3[kk] = W3[(kc + kk) * H + j];
        #pragma unroll
        for (int r = 0; r < ROWS; ++r) {
            float s = acc[r];
            #pragma unroll
            for (int kk = 0; kk < 32; ++kk) s += sH[r][kc + kk] * w3[kk];
            acc[r] = s;
        }
    }
    #pragma unroll
    for (int r = 0; r < ROWS; ++r) outp[(row0 + r) * H + j] = acc[r];
}

// ---------------------------------------------------------------------------
// Kernel 2: scores[a][r] = sum_h relu(pa[a][h] + pr[r][h]) * Ws2[h] + bs2
// 64x64 tile / 256-thread block; 4x4 micro-tile per thread.
// LDS = 2 * 64 * 128 * 4B = 64 KB exactly (known-safe; m132).
// XOR-swizzle (float4-group ^ (row&7)) makes both read patterns <=2-way
// bank aliasing (free per m136). B rows mapped r = tx + 16*j so stores
// coalesce across the 16 tx lanes.
// ---------------------------------------------------------------------------
__global__ __launch_bounds__(256) void pair_kernel(
    const float* __restrict__ pa, const float* __restrict__ pr,
    const float* __restrict__ Ws2, const float* __restrict__ bs2,
    float* __restrict__ out, int nr)
{
    __shared__ float sA[64 * H];
    __shared__ float sB[64 * H];

    const int tid = threadIdx.x;
    const int a0 = blockIdx.y * 64;
    const int r0 = blockIdx.x * 64;

    const float4* pa4 = (const float4*)pa;
    const float4* pr4 = (const float4*)pr;
    #pragma unroll
    for (int i = 0; i < 8; ++i) {
        int idx = i * 256 + tid;          // 0..2047
        int row = idx >> 5;               // 0..63
        int c4  = idx & 31;               // float4 group 0..31
        int p   = (c4 ^ (row & 7)) << 2;  // swizzled float offset
        *(float4*)&sA[row * H + p] = pa4[(a0 + row) * (H / 4) + c4];
        *(float4*)&sB[row * H + p] = pr4[(r0 + row) * (H / 4) + c4];
    }
    __syncthreads();

    const int tx = tid & 15;   // r dimension
    const int ty = tid >> 4;   // a dimension

    int rowA[4], rowB[4];
    #pragma unroll
    for (int i = 0; i < 4; ++i) rowA[i] = ty * 4 + i;
    #pragma unroll
    for (int j = 0; j < 4; ++j) rowB[j] = tx + 16 * j;

    f2 acc[4][4];
    #pragma unroll
    for (int i = 0; i < 4; ++i)
        #pragma unroll
        for (int j = 0; j < 4; ++j) acc[i][j] = (f2){0.f, 0.f};

    const float4* w4 = (const float4*)Ws2;   // wave-uniform -> s_load
    const f2 zero = {0.f, 0.f};

    #pragma unroll 4
    for (int h4 = 0; h4 < H / 4; ++h4) {
        float4 wv = w4[h4];
        f2 wlo = {wv.x, wv.y}, whi = {wv.z, wv.w};
        float4 av[4], bv[4];
        #pragma unroll
        for (int i = 0; i < 4; ++i)
            av[i] = *(const float4*)&sA[rowA[i] * H + ((h4 ^ (rowA[i] & 7)) << 2)];
        #pragma unroll
        for (int j = 0; j < 4; ++j)
            bv[j] = *(const float4*)&sB[rowB[j] * H + ((h4 ^ (rowB[j] & 7)) << 2)];
        #pragma unroll
        for (int i = 0; i < 4; ++i) {
            f2 alo = {av[i].x, av[i].y}, ahi = {av[i].z, av[i].w};
            #pragma unroll
            for (int j = 0; j < 4; ++j) {
                f2 blo = {bv[j].x, bv[j].y}, bhi = {bv[j].z, bv[j].w};
                f2 zlo = __builtin_elementwise_max(alo + blo, zero);
                f2 zhi = __builtin_elementwise_max(ahi + bhi, zero);
                acc[i][j] += zlo * wlo;   // -> v_pk_fma_f32 (ffp-contract)
                acc[i][j] += zhi * whi;
            }
        }
    }

    const float b2v = bs2[0];
    #pragma unroll
    for (int i = 0; i < 4; ++i) {
        int a = a0 + rowA[i];
        #pragma unroll
        for (int j = 0; j < 4; ++j) {
            out[(long)a * nr + (r0 + rowB[j])] = acc[i][j].x + acc[i][j].y + b2v;
        }
    }
}

extern "C" void kernel_launch(void* const* d_in, const int* in_sizes, int n_in,
                              void* d_out, int out_size, void* d_ws, size_t ws_size,
                              hipStream_t stream) {
    const float* xA  = (const float*)d_in[0];
    const float* xR  = (const float*)d_in[1];
    const float* Wa1 = (const float*)d_in[2];
    const float* ba1 = (const float*)d_in[3];
    const float* Wa2 = (const float*)d_in[4];
    const float* ba2 = (const float*)d_in[5];
    const float* Wr1 = (const float*)d_in[6];
    const float* br1 = (const float*)d_in[7];
    const float* Wr2 = (const float*)d_in[8];
    const float* br2 = (const float*)d_in[9];
    const float* Ws1 = (const float*)d_in[10];
    const float* bs1 = (const float*)d_in[11];
    const float* Ws2 = (const float*)d_in[12];
    const float* bs2 = (const float*)d_in[13];
    float* out = (float*)d_out;

    const int na = in_sizes[0] / 24;   // 1024
    const int nr = in_sizes[1] / 20;   // 1024

    float* pa = (float*)d_ws;                       // na*128 floats (bs1 folded in)
    float* pr = pa + (size_t)na * H;                // nr*128 floats

    emb_kernel<<<dim3(na / 8 + nr / 8), 128, 0, stream>>>(
        xA, xR, Wa1, ba1, Wa2, ba2, Wr1, br1, Wr2, br2, Ws1, bs1, pa, pr, na, nr);

    pair_kernel<<<dim3(nr / 64, na / 64), 256, 0, stream>>>(
        pa, pr, Ws2, bs2, out, nr);
}

// Round 2
// 104.721 us; speedup vs baseline: 1.0183x; 1.0183x over previous
//
#include <hip/hip_runtime.h>

#define H 128

typedef float f2 __attribute__((ext_vector_type(2)));

// ---------------------------------------------------------------------------
// Kernel 1: fused 3-layer MLP + Ws1 projection for agents AND regions.
//   agent blocks: pa[a][:] = relu(relu(xA@Wa1+ba1)@Wa2+ba2) @ Ws1[:128] + bs1
//   region blocks: pr[r][:] = relu(relu(xR@Wr1+br1)@Wr2+br2) @ Ws1[128:]
// (bs1 folded into pa so the pair kernel only does pa+pr.)
// Block = 128 threads (thread j owns output column j), 8 rows per block.
// All LDS activation reads are float4 (broadcast, conflict-free) — 4x fewer
// LDS instructions than the scalar-read version.
// ---------------------------------------------------------------------------
__global__ __launch_bounds__(128) void emb_kernel(
    const float* __restrict__ xA, const float* __restrict__ xR,
    const float* __restrict__ Wa1, const float* __restrict__ ba1,
    const float* __restrict__ Wa2, const float* __restrict__ ba2,
    const float* __restrict__ Wr1, const float* __restrict__ br1,
    const float* __restrict__ Wr2, const float* __restrict__ br2,
    const float* __restrict__ Ws1, const float* __restrict__ bs1,
    float* __restrict__ pa, float* __restrict__ pr,
    int na, int nr)
{
    const int ROWS = 8;
    const int b = blockIdx.x;
    const int nblkA = na / ROWS;
    const bool isA = (b < nblkA);                 // wave-uniform branch
    const int row0 = (isA ? b : b - nblkA) * ROWS;
    const float* __restrict__ x  = isA ? xA : xR;
    const float* __restrict__ W1 = isA ? Wa1 : Wr1;
    const float* __restrict__ b1 = isA ? ba1 : br1;
    const float* __restrict__ W2 = isA ? Wa2 : Wr2;
    const float* __restrict__ b2 = isA ? ba2 : br2;
    const float* __restrict__ W3 = isA ? Ws1 : Ws1 + H * H; // Ws1_a / Ws1_r
    float* __restrict__ outp     = isA ? pa : pr;
    const int in_dim = isA ? 24 : 20;

    __shared__ __align__(16) float sX[ROWS][24];   // row stride 96 B (16B mult)
    __shared__ __align__(16) float sH[ROWS][H];

    const int j = threadIdx.x;

    // stage x rows (zero-pad columns >= in_dim so a fixed-24 unroll is safe)
    #pragma unroll
    for (int t = 0; t < 2; ++t) {
        int idx = t * 128 + j;
        if (idx < ROWS * 24) {
            int r = idx / 24, k = idx - r * 24;
            sX[r][k] = (k < in_dim) ? x[(row0 + r) * in_dim + k] : 0.f;
        }
    }
    __syncthreads();

    // ---- layer 1: h1 = relu(x @ W1 + b1) ----
    float w1[24];
    #pragma unroll
    for (int k = 0; k < 24; ++k)
        w1[k] = (k < in_dim) ? W1[k * H + j] : 0.f;   // predicated, no OOB
    {
        const float bj = b1[j];
        #pragma unroll
        for (int r = 0; r < ROWS; ++r) {
            const float4* sx4 = (const float4*)&sX[r][0];
            float s = bj;
            #pragma unroll
            for (int k4 = 0; k4 < 6; ++k4) {
                float4 xv = sx4[k4];
                s += xv.x * w1[k4 * 4 + 0];
                s += xv.y * w1[k4 * 4 + 1];
                s += xv.z * w1[k4 * 4 + 2];
                s += xv.w * w1[k4 * 4 + 3];
            }
            sH[r][j] = fmaxf(s, 0.f);
        }
    }
    __syncthreads();

    float acc[ROWS];
    // ---- layer 2: h2 = relu(h1 @ W2 + b2) ----
    {
        const float bj = b2[j];
        #pragma unroll
        for (int r = 0; r < ROWS; ++r) acc[r] = bj;
    }
    #pragma unroll
    for (int kc = 0; kc < H; kc += 32) {
        float w2[32];
        #pragma unroll
        for (int kk = 0; kk < 32; ++kk) w2[kk] = W2[(kc + kk) * H + j];
        #pragma unroll
        for (int r = 0; r < ROWS; ++r) {
            const float4* sh4 = (const float4*)&sH[r][kc];
            float s = acc[r];
            #pragma unroll
            for (int k4 = 0; k4 < 8; ++k4) {
                float4 hv = sh4[k4];
                s += hv.x * w2[k4 * 4 + 0];
                s += hv.y * w2[k4 * 4 + 1];
                s += hv.z * w2[k4 * 4 + 2];
                s += hv.w * w2[k4 * 4 + 3];
            }
            acc[r] = s;
        }
    }
    __syncthreads();
    #pragma unroll
    for (int r = 0; r < ROWS; ++r) sH[r][j] = fmaxf(acc[r], 0.f);
    __syncthreads();

    // ---- layer 3 (projection): p = h2 @ W3 (+ bs1 on agent side) ----
    {
        const float init = isA ? bs1[j] : 0.f;
        #pragma unroll
        for (int r = 0; r < ROWS; ++r) acc[r] = init;
    }
    #pragma unroll
    for (int kc = 0; kc < H; kc += 32) {
        float w3[32];
        #pragma unroll
        for (int kk = 0; kk < 32; ++kk) w3[kk] = W3[(kc + kk) * H + j];
        #pragma unroll
        for (int r = 0; r < ROWS; ++r) {
            const float4* sh4 = (const float4*)&sH[r][kc];
            float s = acc[r];
            #pragma unroll
            for (int k4 = 0; k4 < 8; ++k4) {
                float4 hv = sh4[k4];
                s += hv.x * w3[k4 * 4 + 0];
                s += hv.y * w3[k4 * 4 + 1];
                s += hv.z * w3[k4 * 4 + 2];
                s += hv.w * w3[k4 * 4 + 3];
            }
            acc[r] = s;
        }
    }
    #pragma unroll
    for (int r = 0; r < ROWS; ++r) outp[(row0 + r) * H + j] = acc[r];
}

// ---------------------------------------------------------------------------
// Kernel 2: scores[a][r] = sum_h relu(pa[a][h] + pr[r][h]) * Ws2[h] + bs2
// 64x64 tile / 256-thread block; 4x4 micro-tile per thread.
//
// A-fragment reads come straight from GLOBAL (L1): the address depends only
// on ty, so 16 lanes broadcast one 16B line; the block's A-slice is
// 64 rows x 512 B = 32 KB = L1-resident. This halves LDS-pipe traffic vs
// staging A in LDS (the previous version was LDS-pipe-bound at 8 reads/iter
// vs a 4-read/iter balance point).
//
// B stays in LDS (per-lane addresses), XOR-swizzled so the 16-row read
// pattern is 2-way bank aliasing (free, m136). LDS = 32 KB.
// ---------------------------------------------------------------------------
__global__ __launch_bounds__(256) void pair_kernel(
    const float* __restrict__ pa, const float* __restrict__ pr,
    const float* __restrict__ Ws2, const float* __restrict__ bs2,
    float* __restrict__ out, int nr)
{
    __shared__ float sB[64 * H];

    const int tid = threadIdx.x;
    const int a0 = blockIdx.y * 64;
    const int r0 = blockIdx.x * 64;

    const float4* pr4 = (const float4*)pr;
    #pragma unroll
    for (int i = 0; i < 8; ++i) {
        int idx = i * 256 + tid;          // 0..2047
        int row = idx >> 5;               // 0..63
        int c4  = idx & 31;               // float4 group 0..31
        int p   = (c4 ^ (row & 7)) << 2;  // swizzled float offset
        *(float4*)&sB[row * H + p] = pr4[(r0 + row) * (H / 4) + c4];
    }
    __syncthreads();

    const int tx = tid & 15;   // r dimension
    const int ty = tid >> 4;   // a dimension
    const int sw7 = tx & 7;    // thread-constant part of the B swizzle

    const float4* pa4 = (const float4*)pa;
    long aBase[4];             // float4 index of row (a0+ty*4+i)
    #pragma unroll
    for (int i = 0; i < 4; ++i) aBase[i] = (long)(a0 + ty * 4 + i) * (H / 4);
    int bBase[4];              // float index of row (tx+16j) in sB
    #pragma unroll
    for (int j = 0; j < 4; ++j) bBase[j] = (tx + 16 * j) * H;

    f2 acc[4][4];
    #pragma unroll
    for (int i = 0; i < 4; ++i)
        #pragma unroll
        for (int j = 0; j < 4; ++j) acc[i][j] = (f2){0.f, 0.f};

    const float4* w4 = (const float4*)Ws2;   // wave-uniform -> s_load
    const f2 zero = {0.f, 0.f};

    #pragma unroll 4
    for (int h4 = 0; h4 < H / 4; ++h4) {
        float4 wv = w4[h4];
        f2 wlo = {wv.x, wv.y}, whi = {wv.z, wv.w};
        const int sw = (h4 ^ sw7) << 2;       // B swizzle offset this step
        float4 av[4], bv[4];
        #pragma unroll
        for (int i = 0; i < 4; ++i)
            av[i] = pa4[aBase[i] + h4];       // global, 16-lane broadcast, L1
        #pragma unroll
        for (int j = 0; j < 4; ++j)
            bv[j] = *(const float4*)&sB[bBase[j] + sw];
        #pragma unroll
        for (int i = 0; i < 4; ++i) {
            f2 alo = {av[i].x, av[i].y}, ahi = {av[i].z, av[i].w};
            #pragma unroll
            for (int j = 0; j < 4; ++j) {
                f2 blo = {bv[j].x, bv[j].y}, bhi = {bv[j].z, bv[j].w};
                f2 zlo = __builtin_elementwise_max(alo + blo, zero);
                f2 zhi = __builtin_elementwise_max(ahi + bhi, zero);
                acc[i][j] += zlo * wlo;   // -> v_pk_fma_f32
                acc[i][j] += zhi * whi;
            }
        }
    }

    const float b2v = bs2[0];
    #pragma unroll
    for (int i = 0; i < 4; ++i) {
        int a = a0 + ty * 4 + i;
        #pragma unroll
        for (int j = 0; j < 4; ++j) {
            out[(long)a * nr + (r0 + tx + 16 * j)] = acc[i][j].x + acc[i][j].y + b2v;
        }
    }
}

extern "C" void kernel_launch(void* const* d_in, const int* in_sizes, int n_in,
                              void* d_out, int out_size, void* d_ws, size_t ws_size,
                              hipStream_t stream) {
    const float* xA  = (const float*)d_in[0];
    const float* xR  = (const float*)d_in[1];
    const float* Wa1 = (const float*)d_in[2];
    const float* ba1 = (const float*)d_in[3];
    const float* Wa2 = (const float*)d_in[4];
    const float* ba2 = (const float*)d_in[5];
    const float* Wr1 = (const float*)d_in[6];
    const float* br1 = (const float*)d_in[7];
    const float* Wr2 = (const float*)d_in[8];
    const float* br2 = (const float*)d_in[9];
    const float* Ws1 = (const float*)d_in[10];
    const float* bs1 = (const float*)d_in[11];
    const float* Ws2 = (const float*)d_in[12];
    const float* bs2 = (const float*)d_in[13];
    float* out = (float*)d_out;

    const int na = in_sizes[0] / 24;   // 1024
    const int nr = in_sizes[1] / 20;   // 1024

    float* pa = (float*)d_ws;                       // na*128 floats (bs1 folded in)
    float* pr = pa + (size_t)na * H;                // nr*128 floats

    emb_kernel<<<dim3(na / 8 + nr / 8), 128, 0, stream>>>(
        xA, xR, Wa1, ba1, Wa2, ba2, Wr1, br1, Wr2, br2, Ws1, bs1, pa, pr, na, nr);

    pair_kernel<<<dim3(nr / 64, na / 64), 256, 0, stream>>>(
        pa, pr, Ws2, bs2, out, nr);
}

// Round 3
// 101.449 us; speedup vs baseline: 1.0512x; 1.0323x over previous
//
#include <hip/hip_runtime.h>

#define H 128

typedef float f2 __attribute__((ext_vector_type(2)));

// ---------------------------------------------------------------------------
// Kernel 1: fused 3-layer MLP + Ws1 projection for agents AND regions.
//   agent blocks: pa[a][:] = relu(relu(xA@Wa1+ba1)@Wa2+ba2) @ Ws1[:128] + bs1
//   region blocks: pr[r][:] = relu(relu(xR@Wr1+br1)@Wr2+br2) @ Ws1[128:]
// Block = 256 threads = two independent 4-row groups (g = tid>>7), thread
// j = tid&127 owns output column j of its group's rows. 256 blocks total
// -> 8 waves/CU = 2 waves/SIMD (was 0.5) for latency hiding.
// ---------------------------------------------------------------------------
__global__ __launch_bounds__(256) void emb_kernel(
    const float* __restrict__ xA, const float* __restrict__ xR,
    const float* __restrict__ Wa1, const float* __restrict__ ba1,
    const float* __restrict__ Wa2, const float* __restrict__ ba2,
    const float* __restrict__ Wr1, const float* __restrict__ br1,
    const float* __restrict__ Wr2, const float* __restrict__ br2,
    const float* __restrict__ Ws1, const float* __restrict__ bs1,
    float* __restrict__ pa, float* __restrict__ pr,
    int na, int nr)
{
    const int ROWS = 8;                 // per block; 4 per half-block group
    const int b = blockIdx.x;
    const int nblkA = na / ROWS;
    const bool isA = (b < nblkA);                 // wave-uniform branch
    const int row0 = (isA ? b : b - nblkA) * ROWS;
    const float* __restrict__ x  = isA ? xA : xR;
    const float* __restrict__ W1 = isA ? Wa1 : Wr1;
    const float* __restrict__ b1 = isA ? ba1 : br1;
    const float* __restrict__ W2 = isA ? Wa2 : Wr2;
    const float* __restrict__ b2 = isA ? ba2 : br2;
    const float* __restrict__ W3 = isA ? Ws1 : Ws1 + H * H; // Ws1_a / Ws1_r
    float* __restrict__ outp     = isA ? pa : pr;
    const int in_dim = isA ? 24 : 20;

    __shared__ __align__(16) float sX[ROWS][24];   // row stride 96 B
    __shared__ __align__(16) float sH[ROWS][H];

    const int tid = threadIdx.x;
    const int j = tid & 127;            // output column
    const int g = tid >> 7;             // row group: rows g*4 .. g*4+3
    const int r0g = g * 4;

    // stage x rows (zero-pad columns >= in_dim so a fixed-24 unroll is safe)
    {
        int idx = tid;                  // 0..255, need 0..191
        if (idx < ROWS * 24) {
            int r = idx / 24, k = idx - r * 24;
            sX[r][k] = (k < in_dim) ? x[(row0 + r) * in_dim + k] : 0.f;
        }
    }
    __syncthreads();

    // ---- layer 1: h1 = relu(x @ W1 + b1), 4 rows per thread ----
    float w1[24];
    #pragma unroll
    for (int k = 0; k < 24; ++k)
        w1[k] = (k < in_dim) ? W1[k * H + j] : 0.f;   // predicated, no OOB
    {
        const float bj = b1[j];
        #pragma unroll
        for (int r = 0; r < 4; ++r) {
            const float4* sx4 = (const float4*)&sX[r0g + r][0];
            float s = bj;
            #pragma unroll
            for (int k4 = 0; k4 < 6; ++k4) {
                float4 xv = sx4[k4];
                s += xv.x * w1[k4 * 4 + 0];
                s += xv.y * w1[k4 * 4 + 1];
                s += xv.z * w1[k4 * 4 + 2];
                s += xv.w * w1[k4 * 4 + 3];
            }
            sH[r0g + r][j] = fmaxf(s, 0.f);
        }
    }
    __syncthreads();

    float acc[4];
    // ---- layer 2: h2 = relu(h1 @ W2 + b2) ----
    {
        const float bj = b2[j];
        #pragma unroll
        for (int r = 0; r < 4; ++r) acc[r] = bj;
    }
    #pragma unroll
    for (int kc = 0; kc < H; kc += 32) {
        float w2[32];
        #pragma unroll
        for (int kk = 0; kk < 32; ++kk) w2[kk] = W2[(kc + kk) * H + j];
        #pragma unroll
        for (int r = 0; r < 4; ++r) {
            const float4* sh4 = (const float4*)&sH[r0g + r][kc];
            float s = acc[r];
            #pragma unroll
            for (int k4 = 0; k4 < 8; ++k4) {
                float4 hv = sh4[k4];
                s += hv.x * w2[k4 * 4 + 0];
                s += hv.y * w2[k4 * 4 + 1];
                s += hv.z * w2[k4 * 4 + 2];
                s += hv.w * w2[k4 * 4 + 3];
            }
            acc[r] = s;
        }
    }
    __syncthreads();
    #pragma unroll
    for (int r = 0; r < 4; ++r) sH[r0g + r][j] = fmaxf(acc[r], 0.f);
    __syncthreads();

    // ---- layer 3 (projection): p = h2 @ W3 (+ bs1 on agent side) ----
    {
        const float init = isA ? bs1[j] : 0.f;
        #pragma unroll
        for (int r = 0; r < 4; ++r) acc[r] = init;
    }
    #pragma unroll
    for (int kc = 0; kc < H; kc += 32) {
        float w3[32];
        #pragma unroll
        for (int kk = 0; kk < 32; ++kk) w3[kk] = W3[(kc + kk) * H + j];
        #pragma unroll
        for (int r = 0; r < 4; ++r) {
            const float4* sh4 = (const float4*)&sH[r0g + r][kc];
            float s = acc[r];
            #pragma unroll
            for (int k4 = 0; k4 < 8; ++k4) {
                float4 hv = sh4[k4];
                s += hv.x * w3[k4 * 4 + 0];
                s += hv.y * w3[k4 * 4 + 1];
                s += hv.z * w3[k4 * 4 + 2];
                s += hv.w * w3[k4 * 4 + 3];
            }
            acc[r] = s;
        }
    }
    #pragma unroll
    for (int r = 0; r < 4; ++r) outp[(row0 + r0g + r) * H + j] = acc[r];
}

// ---------------------------------------------------------------------------
// Kernel 2: scores[a][r] = sum_h relu(pa[a][h] + pr[r][h]) * Ws2[h] + bs2
// 64A x 32B tile / 256-thread block; micro-tile 4x2 per thread.
// Grid 32x16 = 512 blocks = 2 blocks/CU = 8 waves/CU = 2 waves/SIMD
// (the previous 64x64 config ran 1 wave/SIMD -> exposed LDS/L1 latency).
// Pipe balance per CU per h4-step: LDS 8 waves x 2 ds_read_b128 x 12cyc
// = 192 cyc == VALU 2 waves/SIMD x 48 pk-instr x 2 cyc = 192 cyc.
// A-fragments come from global/L1 (address depends only on ty -> 4 unique
// 16B lines per instr, block A-slice 32 KB = L1-resident).
// B in LDS, XOR-swizzled; tx is 16-wide so reads are 2-way aliased = free.
// ---------------------------------------------------------------------------
__global__ __launch_bounds__(256) void pair_kernel(
    const float* __restrict__ pa, const float* __restrict__ pr,
    const float* __restrict__ Ws2, const float* __restrict__ bs2,
    float* __restrict__ out, int nr)
{
    __shared__ float sB[32 * H];        // 16 KB

    const int tid = threadIdx.x;
    const int a0 = blockIdx.y * 64;
    const int r0 = blockIdx.x * 32;

    const float4* pr4 = (const float4*)pr;
    #pragma unroll
    for (int i = 0; i < 4; ++i) {
        int idx = i * 256 + tid;          // 0..1023
        int row = idx >> 5;               // 0..31
        int c4  = idx & 31;               // float4 group 0..31
        int p   = (c4 ^ (row & 7)) << 2;  // swizzled float offset
        *(float4*)&sB[row * H + p] = pr4[(r0 + row) * (H / 4) + c4];
    }
    __syncthreads();

    const int tx = tid & 15;   // r dimension (16-wide: keeps swizzle 2-way)
    const int ty = tid >> 4;   // a dimension 0..15
    const int sw7 = tx & 7;    // thread-constant part of the B swizzle

    const float4* pa4 = (const float4*)pa;
    long aBase[4];             // float4 index of row (a0+ty*4+i)
    #pragma unroll
    for (int i = 0; i < 4; ++i) aBase[i] = (long)(a0 + ty * 4 + i) * (H / 4);
    int bBase[2];              // float index of row (tx+16j) in sB
    #pragma unroll
    for (int j = 0; j < 2; ++j) bBase[j] = (tx + 16 * j) * H;

    f2 acc[4][2];
    #pragma unroll
    for (int i = 0; i < 4; ++i)
        #pragma unroll
        for (int j = 0; j < 2; ++j) acc[i][j] = (f2){0.f, 0.f};

    const float4* w4 = (const float4*)Ws2;   // wave-uniform -> s_load
    const f2 zero = {0.f, 0.f};

    #pragma unroll 8
    for (int h4 = 0; h4 < H / 4; ++h4) {
        float4 wv = w4[h4];
        f2 wlo = {wv.x, wv.y}, whi = {wv.z, wv.w};
        const int sw = (h4 ^ sw7) << 2;       // B swizzle offset this step
        float4 av[4], bv[2];
        #pragma unroll
        for (int i = 0; i < 4; ++i)
            av[i] = pa4[aBase[i] + h4];       // global, L1 broadcast
        #pragma unroll
        for (int j = 0; j < 2; ++j)
            bv[j] = *(const float4*)&sB[bBase[j] + sw];
        #pragma unroll
        for (int i = 0; i < 4; ++i) {
            f2 alo = {av[i].x, av[i].y}, ahi = {av[i].z, av[i].w};
            #pragma unroll
            for (int j = 0; j < 2; ++j) {
                f2 blo = {bv[j].x, bv[j].y}, bhi = {bv[j].z, bv[j].w};
                f2 zlo = __builtin_elementwise_max(alo + blo, zero);
                f2 zhi = __builtin_elementwise_max(ahi + bhi, zero);
                acc[i][j] += zlo * wlo;   // -> v_pk_fma_f32
                acc[i][j] += zhi * whi;
            }
        }
    }

    const float b2v = bs2[0];
    #pragma unroll
    for (int i = 0; i < 4; ++i) {
        int a = a0 + ty * 4 + i;
        #pragma unroll
        for (int j = 0; j < 2; ++j) {
            out[(long)a * nr + (r0 + tx + 16 * j)] = acc[i][j].x + acc[i][j].y + b2v;
        }
    }
}

extern "C" void kernel_launch(void* const* d_in, const int* in_sizes, int n_in,
                              void* d_out, int out_size, void* d_ws, size_t ws_size,
                              hipStream_t stream) {
    const float* xA  = (const float*)d_in[0];
    const float* xR  = (const float*)d_in[1];
    const float* Wa1 = (const float*)d_in[2];
    const float* ba1 = (const float*)d_in[3];
    const float* Wa2 = (const float*)d_in[4];
    const float* ba2 = (const float*)d_in[5];
    const float* Wr1 = (const float*)d_in[6];
    const float* br1 = (const float*)d_in[7];
    const float* Wr2 = (const float*)d_in[8];
    const float* br2 = (const float*)d_in[9];
    const float* Ws1 = (const float*)d_in[10];
    const float* bs1 = (const float*)d_in[11];
    const float* Ws2 = (const float*)d_in[12];
    const float* bs2 = (const float*)d_in[13];
    float* out = (float*)d_out;

    const int na = in_sizes[0] / 24;   // 1024
    const int nr = in_sizes[1] / 20;   // 1024

    float* pa = (float*)d_ws;                       // na*128 floats (bs1 folded in)
    float* pr = pa + (size_t)na * H;                // nr*128 floats

    emb_kernel<<<dim3(na / 8 + nr / 8), 256, 0, stream>>>(
        xA, xR, Wa1, ba1, Wa2, ba2, Wr1, br1, Wr2, br2, Ws1, bs1, pa, pr, na, nr);

    pair_kernel<<<dim3(nr / 32, na / 64), 256, 0, stream>>>(
        pa, pr, Ws2, bs2, out, nr);
}